// Round 1
// baseline (3166.032 us; speedup 1.0000x reference)
//
#include <hip/hip_runtime.h>

#define RES 32
#define R3 (RES * RES * RES)
#define BATCH 16
#define CCH 64
#define NPTS 65536

// ---------------- Kernel 1: per-batch mean + max radius ----------------
__global__ void stats_kernel(const float* __restrict__ coords,
                             float* __restrict__ stats) {
    const int b = blockIdx.x;
    const float* cb = coords + (size_t)b * 3 * NPTS;
    const int tid = threadIdx.x;
    const int nthr = blockDim.x;

    float sx = 0.f, sy = 0.f, sz = 0.f;
    for (int n = tid; n < NPTS; n += nthr) {
        sx += cb[n];
        sy += cb[NPTS + n];
        sz += cb[2 * NPTS + n];
    }
    __shared__ float red[256 * 3];
    red[tid] = sx; red[256 + tid] = sy; red[512 + tid] = sz;
    __syncthreads();
    for (int s = 128; s > 0; s >>= 1) {
        if (tid < s) {
            red[tid]       += red[tid + s];
            red[256 + tid] += red[256 + tid + s];
            red[512 + tid] += red[512 + tid + s];
        }
        __syncthreads();
    }
    __shared__ float mean[3];
    if (tid == 0) {
        mean[0] = red[0]   / (float)NPTS;
        mean[1] = red[256] / (float)NPTS;
        mean[2] = red[512] / (float)NPTS;
    }
    __syncthreads();
    const float mx = mean[0], my = mean[1], mz = mean[2];

    float r2max = 0.f;
    for (int n = tid; n < NPTS; n += nthr) {
        float x = cb[n] - mx;
        float y = cb[NPTS + n] - my;
        float z = cb[2 * NPTS + n] - mz;
        float r2 = x * x + y * y + z * z;
        r2max = fmaxf(r2max, r2);
    }
    red[tid] = r2max;
    __syncthreads();
    for (int s = 128; s > 0; s >>= 1) {
        if (tid < s) red[tid] = fmaxf(red[tid], red[tid + s]);
        __syncthreads();
    }
    if (tid == 0) {
        stats[b * 4 + 0] = mx;
        stats[b * 4 + 1] = my;
        stats[b * 4 + 2] = mz;
        stats[b * 4 + 3] = sqrtf(red[0]);   // max L2 norm (sqrt monotonic)
    }
}

// -------- Kernel 2: normalized coords (output 2), voxel idx, counts --------
__global__ void norm_idx_kernel(const float* __restrict__ coords,
                                const float* __restrict__ stats,
                                float* __restrict__ out_norm,
                                int* __restrict__ idx,
                                unsigned int* __restrict__ counts) {
    const int tid = blockIdx.x * blockDim.x + threadIdx.x;
    if (tid >= BATCH * NPTS) return;
    const int b = tid >> 16;          // NPTS = 65536
    const int n = tid & (NPTS - 1);

    const float mx = stats[b * 4 + 0];
    const float my = stats[b * 4 + 1];
    const float mz = stats[b * 4 + 2];
    const float denom = stats[b * 4 + 3] * 2.0f;   // radius*2 + EPS(=0)

    const float* cb = coords + (size_t)b * 3 * NPTS;
    float x = (cb[n]            - mx) / denom + 0.5f;
    float y = (cb[NPTS + n]     - my) / denom + 0.5f;
    float z = (cb[2 * NPTS + n] - mz) / denom + 0.5f;

    // clip(norm * R, 0, R-1) — this clipped value IS the norm_coords output
    x = fminf(fmaxf(x * (float)RES, 0.f), (float)(RES - 1));
    y = fminf(fmaxf(y * (float)RES, 0.f), (float)(RES - 1));
    z = fminf(fmaxf(z * (float)RES, 0.f), (float)(RES - 1));

    float* ob = out_norm + (size_t)b * 3 * NPTS;
    ob[n]            = x;
    ob[NPTS + n]     = y;
    ob[2 * NPTS + n] = z;

    // round-half-to-even to match jnp.round
    const int vx = (int)rintf(x);
    const int vy = (int)rintf(y);
    const int vz = (int)rintf(z);
    const int flat = (vx * RES + vy) * RES + vz;

    idx[tid] = flat;
    atomicAdd(&counts[b * R3 + flat], 1u);
}

// ---------------- Kernel 3: atomic scatter of features ----------------
// thread = 4 consecutive points of one (b,c): float4 coalesced read,
// 4 scattered f32 atomics into d_out (already [b][c][v] layout).
__global__ void scatter_kernel(const float* __restrict__ features,
                               const int* __restrict__ idx,
                               float* __restrict__ vox) {
    const size_t tid = (size_t)blockIdx.x * blockDim.x + threadIdx.x;
    const int per_bc = NPTS / 4;                 // 16384
    const int n4 = (int)(tid % per_bc);
    const int bc = (int)(tid / per_bc);          // b*CCH + c
    if (bc >= BATCH * CCH) return;
    const int b = bc >> 6;                       // CCH = 64

    const float4 f = reinterpret_cast<const float4*>(
                         features + (size_t)bc * NPTS)[n4];
    const int4 i4 = reinterpret_cast<const int4*>(
                         idx + (size_t)b * NPTS)[n4];

    float* base = vox + (size_t)bc * R3;
    atomicAdd(base + i4.x, f.x);
    atomicAdd(base + i4.y, f.y);
    atomicAdd(base + i4.z, f.z);
    atomicAdd(base + i4.w, f.w);
}

// ---------------- Kernel 4: divide by counts (in place) ----------------
__global__ void finalize_kernel(float* __restrict__ vox,
                                const unsigned int* __restrict__ counts) {
    const size_t tid = (size_t)blockIdx.x * blockDim.x + threadIdx.x;
    const size_t total4 = (size_t)BATCH * CCH * R3 / 4;
    if (tid >= total4) return;
    const int per_bc = R3 / 4;                   // 8192
    const int v4 = (int)(tid % per_bc);
    const int bc = (int)(tid / per_bc);
    const int b = bc >> 6;

    float4 s = reinterpret_cast<float4*>(vox)[tid];
    const uint4 c = reinterpret_cast<const uint4*>(counts + (size_t)b * R3)[v4];
    s.x /= fmaxf((float)c.x, 1.f);
    s.y /= fmaxf((float)c.y, 1.f);
    s.z /= fmaxf((float)c.z, 1.f);
    s.w /= fmaxf((float)c.w, 1.f);
    reinterpret_cast<float4*>(vox)[tid] = s;
}

extern "C" void kernel_launch(void* const* d_in, const int* in_sizes, int n_in,
                              void* d_out, int out_size, void* d_ws, size_t ws_size,
                              hipStream_t stream) {
    const float* features = (const float*)d_in[0];   // [16,64,65536]
    const float* coords   = (const float*)d_in[1];   // [16,3,65536]

    float* vox      = (float*)d_out;                           // 33,554,432 f32
    float* out_norm = (float*)d_out + (size_t)BATCH * CCH * R3; // 3,145,728 f32

    // workspace layout
    char* ws = (char*)d_ws;
    float*        stats  = (float*)ws;                       // 256 B
    int*          idx    = (int*)(ws + 256);                  // 4 MiB
    unsigned int* counts = (unsigned int*)(ws + 256 + (size_t)BATCH * NPTS * 4); // 2 MiB

    // zero accumulators (d_out vox region + counts)
    hipMemsetAsync(vox, 0, (size_t)BATCH * CCH * R3 * sizeof(float), stream);
    hipMemsetAsync(counts, 0, (size_t)BATCH * R3 * sizeof(unsigned int), stream);

    stats_kernel<<<BATCH, 256, 0, stream>>>(coords, stats);

    {
        const int total = BATCH * NPTS;
        norm_idx_kernel<<<(total + 255) / 256, 256, 0, stream>>>(
            coords, stats, out_norm, idx, counts);
    }
    {
        const size_t total = (size_t)BATCH * CCH * NPTS / 4;
        scatter_kernel<<<(unsigned)((total + 255) / 256), 256, 0, stream>>>(
            features, idx, vox);
    }
    {
        const size_t total4 = (size_t)BATCH * CCH * R3 / 4;
        finalize_kernel<<<(unsigned)((total4 + 255) / 256), 256, 0, stream>>>(
            vox, counts);
    }
}

// Round 2
// 430.640 us; speedup vs baseline: 7.3519x; 7.3519x over previous
//
#include <hip/hip_runtime.h>

#define RES 32
#define R3 (RES * RES * RES)
#define BATCH 16
#define CCH 64
#define NPTS 65536
#define NPTS4 (NPTS / 4)

// ws layout:
//   sums   : float[16][3]   @ ws + 0     (192 B)
//   r2bits : uint[16]       @ ws + 192   (64 B)
//   idx    : int[16][65536] @ ws + 256   (4 MiB)
//   counts : uint[16][R3]   @ ws + 256 + 4 MiB (2 MiB)

// ---------------- Stats phase A: partial coord sums ----------------
// 256 blocks: 16 per batch, each covers 4096 points.
__global__ void statsA_kernel(const float* __restrict__ coords,
                              float* __restrict__ sums) {
    const int bid = blockIdx.x;      // 0..255
    const int b = bid >> 4;
    const int chunk = bid & 15;
    const int tid = threadIdx.x;     // 0..255
    const float* cb = coords + (size_t)b * 3 * NPTS;
    const int base4 = chunk * 1024;  // 1024 float4 per chunk per row

    float sx = 0.f, sy = 0.f, sz = 0.f;
    for (int k = tid; k < 1024; k += 256) {
        float4 x4 = reinterpret_cast<const float4*>(cb)[base4 + k];
        float4 y4 = reinterpret_cast<const float4*>(cb + NPTS)[base4 + k];
        float4 z4 = reinterpret_cast<const float4*>(cb + 2 * NPTS)[base4 + k];
        sx += (x4.x + x4.y) + (x4.z + x4.w);
        sy += (y4.x + y4.y) + (y4.z + y4.w);
        sz += (z4.x + z4.y) + (z4.z + z4.w);
    }
    __shared__ float red[3][256];
    red[0][tid] = sx; red[1][tid] = sy; red[2][tid] = sz;
    __syncthreads();
    for (int s = 128; s > 0; s >>= 1) {
        if (tid < s) {
            red[0][tid] += red[0][tid + s];
            red[1][tid] += red[1][tid + s];
            red[2][tid] += red[2][tid + s];
        }
        __syncthreads();
    }
    if (tid == 0) {
        atomicAdd(&sums[b * 3 + 0], red[0][0]);
        atomicAdd(&sums[b * 3 + 1], red[1][0]);
        atomicAdd(&sums[b * 3 + 2], red[2][0]);
    }
}

// ---------------- Stats phase B: max squared radius ----------------
__global__ void statsB_kernel(const float* __restrict__ coords,
                              const float* __restrict__ sums,
                              unsigned int* __restrict__ r2bits) {
    const int bid = blockIdx.x;
    const int b = bid >> 4;
    const int chunk = bid & 15;
    const int tid = threadIdx.x;
    const float mx = sums[b * 3 + 0] * (1.0f / NPTS);
    const float my = sums[b * 3 + 1] * (1.0f / NPTS);
    const float mz = sums[b * 3 + 2] * (1.0f / NPTS);
    const float* cb = coords + (size_t)b * 3 * NPTS;
    const int base4 = chunk * 1024;

    float m = 0.f;
    for (int k = tid; k < 1024; k += 256) {
        float4 x4 = reinterpret_cast<const float4*>(cb)[base4 + k];
        float4 y4 = reinterpret_cast<const float4*>(cb + NPTS)[base4 + k];
        float4 z4 = reinterpret_cast<const float4*>(cb + 2 * NPTS)[base4 + k];
        float dx, dy, dz, r2;
        dx = x4.x - mx; dy = y4.x - my; dz = z4.x - mz; r2 = dx*dx + dy*dy + dz*dz; m = fmaxf(m, r2);
        dx = x4.y - mx; dy = y4.y - my; dz = z4.y - mz; r2 = dx*dx + dy*dy + dz*dz; m = fmaxf(m, r2);
        dx = x4.z - mx; dy = y4.z - my; dz = z4.z - mz; r2 = dx*dx + dy*dy + dz*dz; m = fmaxf(m, r2);
        dx = x4.w - mx; dy = y4.w - my; dz = z4.w - mz; r2 = dx*dx + dy*dy + dz*dz; m = fmaxf(m, r2);
    }
    __shared__ float red[256];
    red[tid] = m;
    __syncthreads();
    for (int s = 128; s > 0; s >>= 1) {
        if (tid < s) red[tid] = fmaxf(red[tid], red[tid + s]);
        __syncthreads();
    }
    if (tid == 0)
        atomicMax(&r2bits[b], __float_as_uint(red[0]));  // r2 >= 0: bit order = float order
}

// -------- norm coords (output 2), voxel idx, counts --------
// thread = 4 consecutive points of one batch.
__global__ void norm_idx_kernel(const float* __restrict__ coords,
                                const float* __restrict__ sums,
                                const unsigned int* __restrict__ r2bits,
                                float* __restrict__ out_norm,
                                int* __restrict__ idx,
                                unsigned int* __restrict__ counts) {
    const int t = blockIdx.x * blockDim.x + threadIdx.x;
    if (t >= BATCH * NPTS4) return;
    const int b = t >> 14;           // / 16384
    const int n4 = t & (NPTS4 - 1);

    const float mx = sums[b * 3 + 0] * (1.0f / NPTS);
    const float my = sums[b * 3 + 1] * (1.0f / NPTS);
    const float mz = sums[b * 3 + 2] * (1.0f / NPTS);
    const float denom = 2.0f * sqrtf(__uint_as_float(r2bits[b]));  // radius*2 + EPS(0)

    const float* cb = coords + (size_t)b * 3 * NPTS;
    float4 X = reinterpret_cast<const float4*>(cb)[n4];
    float4 Y = reinterpret_cast<const float4*>(cb + NPTS)[n4];
    float4 Z = reinterpret_cast<const float4*>(cb + 2 * NPTS)[n4];

    float4 Xn, Yn, Zn;
    int4 I;
    unsigned int* cnt = counts + (size_t)b * R3;
    {
        float xs[4] = {X.x, X.y, X.z, X.w};
        float ys[4] = {Y.x, Y.y, Y.z, Y.w};
        float zs[4] = {Z.x, Z.y, Z.z, Z.w};
        float xo[4], yo[4], zo[4];
        int fo[4];
        #pragma unroll
        for (int j = 0; j < 4; ++j) {
            float x = ((xs[j] - mx) / denom + 0.5f) * (float)RES;
            float y = ((ys[j] - my) / denom + 0.5f) * (float)RES;
            float z = ((zs[j] - mz) / denom + 0.5f) * (float)RES;
            x = fminf(fmaxf(x, 0.f), (float)(RES - 1));
            y = fminf(fmaxf(y, 0.f), (float)(RES - 1));
            z = fminf(fmaxf(z, 0.f), (float)(RES - 1));
            xo[j] = x; yo[j] = y; zo[j] = z;
            fo[j] = ((int)rintf(x) * RES + (int)rintf(y)) * RES + (int)rintf(z);
        }
        Xn = make_float4(xo[0], xo[1], xo[2], xo[3]);
        Yn = make_float4(yo[0], yo[1], yo[2], yo[3]);
        Zn = make_float4(zo[0], zo[1], zo[2], zo[3]);
        I  = make_int4(fo[0], fo[1], fo[2], fo[3]);
        #pragma unroll
        for (int j = 0; j < 4; ++j) atomicAdd(&cnt[fo[j]], 1u);
    }

    float* ob = out_norm + (size_t)b * 3 * NPTS;
    reinterpret_cast<float4*>(ob)[n4] = Xn;
    reinterpret_cast<float4*>(ob + NPTS)[n4] = Yn;
    reinterpret_cast<float4*>(ob + 2 * NPTS)[n4] = Zn;
    reinterpret_cast<int4*>(idx + (size_t)b * NPTS)[n4] = I;
}

// ---------------- Scatter: LDS-privatized accumulation ----------------
// One block per (b,c). acc[R3] = 128 KiB LDS. Fuses count-division on write-out.
__global__ __launch_bounds__(1024, 1)
void scatter_lds_kernel(const float* __restrict__ features,
                        const int* __restrict__ idx,
                        const unsigned int* __restrict__ counts,
                        float* __restrict__ vox) {
    __shared__ float acc[R3];                    // 128 KiB
    const int bc = blockIdx.x;                   // b*CCH + c
    const int b = bc >> 6;

    for (int v = threadIdx.x; v < R3 / 4; v += blockDim.x)
        reinterpret_cast<float4*>(acc)[v] = make_float4(0.f, 0.f, 0.f, 0.f);
    __syncthreads();

    const float4* f4 = reinterpret_cast<const float4*>(features + (size_t)bc * NPTS);
    const int4*   i4 = reinterpret_cast<const int4*>(idx + (size_t)b * NPTS);
    for (int n = threadIdx.x; n < NPTS4; n += blockDim.x) {
        float4 f = f4[n];
        int4   i = i4[n];
        atomicAdd(&acc[i.x], f.x);
        atomicAdd(&acc[i.y], f.y);
        atomicAdd(&acc[i.z], f.z);
        atomicAdd(&acc[i.w], f.w);
    }
    __syncthreads();

    const uint4* c4 = reinterpret_cast<const uint4*>(counts + (size_t)b * R3);
    float4* o4 = reinterpret_cast<float4*>(vox + (size_t)bc * R3);
    for (int v = threadIdx.x; v < R3 / 4; v += blockDim.x) {
        float4 s = reinterpret_cast<float4*>(acc)[v];
        uint4 c = c4[v];
        s.x /= fmaxf((float)c.x, 1.f);
        s.y /= fmaxf((float)c.y, 1.f);
        s.z /= fmaxf((float)c.z, 1.f);
        s.w /= fmaxf((float)c.w, 1.f);
        o4[v] = s;
    }
}

extern "C" void kernel_launch(void* const* d_in, const int* in_sizes, int n_in,
                              void* d_out, int out_size, void* d_ws, size_t ws_size,
                              hipStream_t stream) {
    const float* features = (const float*)d_in[0];   // [16,64,65536]
    const float* coords   = (const float*)d_in[1];   // [16,3,65536]

    float* vox      = (float*)d_out;                             // 33,554,432 f32
    float* out_norm = (float*)d_out + (size_t)BATCH * CCH * R3;  // 3,145,728 f32

    char* ws = (char*)d_ws;
    float*        sums   = (float*)ws;                    // 192 B
    unsigned int* r2bits = (unsigned int*)(ws + 192);     // 64 B
    int*          idx    = (int*)(ws + 256);              // 4 MiB
    unsigned int* counts = (unsigned int*)(ws + 256 + (size_t)BATCH * NPTS * 4);

    // zero: stats block (256 B) + counts (2 MiB)
    hipMemsetAsync(ws, 0, 256, stream);
    hipMemsetAsync(counts, 0, (size_t)BATCH * R3 * sizeof(unsigned int), stream);

    statsA_kernel<<<256, 256, 0, stream>>>(coords, sums);
    statsB_kernel<<<256, 256, 0, stream>>>(coords, sums, r2bits);

    {
        const int total = BATCH * NPTS4;                  // 262144 threads
        norm_idx_kernel<<<(total + 255) / 256, 256, 0, stream>>>(
            coords, sums, r2bits, out_norm, idx, counts);
    }

    scatter_lds_kernel<<<BATCH * CCH, 1024, 0, stream>>>(features, idx, counts, vox);
}